// Round 5
// baseline (373.770 us; speedup 1.0000x reference)
//
#include <hip/hip_runtime.h>
#include <hip/hip_bf16.h>

#define B_   2
#define S_   2048
#define D_   2048
#define H_   16
#define KV_  4
#define KQD_ 96
#define VD_  128
#define NQK_ 1920            // H*KQD + KV*KQD = 1536 + 384
#define M_   4096            // B*S

typedef __attribute__((ext_vector_type(8))) short bf16x8;
typedef __attribute__((ext_vector_type(4))) short bf16x4;
typedef __attribute__((ext_vector_type(4))) float f32x4;

__device__ __forceinline__ short f2bf(float f) {
    union { float f; unsigned u; } v; v.f = f;
    unsigned r = (v.u + 0x7fffu + ((v.u >> 16) & 1u)) >> 16;
    return (short)r;
}
__device__ __forceinline__ float bf2f(short s) {
    union { unsigned u; float f; } v; v.u = ((unsigned)(unsigned short)s) << 16;
    return v.f;
}

__device__ __forceinline__ void glds16(const void* g, void* l) {
    __builtin_amdgcn_global_load_lds(
        (__attribute__((address_space(1))) void*)(g),
        (__attribute__((address_space(3))) void*)(l), 16, 0, 0);
}

// DPP-based 16-lane reductions (no LDS/ds_swizzle traffic)
template <int CTRL>
__device__ __forceinline__ float dppf(float x) {
    return __int_as_float(__builtin_amdgcn_update_dpp(
        0, __float_as_int(x), CTRL, 0xF, 0xF, true));
}
__device__ __forceinline__ float rmax16(float x) {
    x = fmaxf(x, dppf<0xB1>(x));    // quad_perm xor1
    x = fmaxf(x, dppf<0x4E>(x));    // quad_perm xor2
    x = fmaxf(x, dppf<0x124>(x));   // row_ror:4
    x = fmaxf(x, dppf<0x128>(x));   // row_ror:8
    return x;
}
__device__ __forceinline__ float rsum16(float x) {
    x += dppf<0xB1>(x);
    x += dppf<0x4E>(x);
    x += dppf<0x124>(x);
    x += dppf<0x128>(x);
    return x;
}

// ---------------------------------------------------------------------------
// fp32 -> bf16 for all five inputs in one launch; dests contiguous in ws.
// ---------------------------------------------------------------------------
__global__ __launch_bounds__(256) void cvt_all(
    const float* __restrict__ hs, const float* __restrict__ wq,
    const float* __restrict__ wk, const float* __restrict__ wv,
    const float* __restrict__ wo, short* __restrict__ dst)
{
    int i = blockIdx.x * 256 + threadIdx.x;
    if (i >= 4390912) return;
    const float* s; int off;
    if      (i < 2097152) { s = hs; off = i; }
    else if (i < 2883584) { s = wq; off = i - 2097152; }
    else if (i < 3080192) { s = wk; off = i - 2883584; }
    else if (i < 3342336) { s = wv; off = i - 3080192; }
    else                  { s = wo; off = i - 3342336; }
    float4 v = ((const float4*)s)[off];
    bf16x4 o;
    o.x = f2bf(v.x); o.y = f2bf(v.y); o.z = f2bf(v.z); o.w = f2bf(v.w);
    ((bf16x4*)dst)[i] = o;
}

// ---------------------------------------------------------------------------
// GEMM: C[M x N] = A[M x K] * W[N x K]^T   (bf16 in, fp32 acc)
// Double-buffered LDS K-loop, ONE barrier per iter: glds(k+1) issued after
// frag reads of tile k and left in flight through the MFMA block; the next
// iteration's __syncthreads (vmcnt(0)) lands it with its latency hidden.
// OUT==2: fp32 row-major.  OUT==3: fused QKV (cols<NQK_ row-major into Cv,
// cols>=NQK_ transposed V^T into Cv2).
// ---------------------------------------------------------------------------
template <int OUT>
__global__ __launch_bounds__(256) void gemm_bt(
    const short* __restrict__ A, const short* __restrict__ W,
    void* __restrict__ Cv, void* __restrict__ Cv2, int M, int N, int K)
{
    __shared__ short As[2][128 * 32];   // 16 KB
    __shared__ short Ws[2][128 * 32];   // 16 KB

    const int tid  = threadIdx.x;
    const int wv   = tid >> 6;
    const int lane = tid & 63;
    const int wm   = wv >> 1, wn = wv & 1;
    const int m0   = blockIdx.x * 128;
    const int n0   = blockIdx.y * 128;
    const int l16  = lane & 15;
    const int qd   = lane >> 4;

    auto stage = [&](int k0, int buf) {
#pragma unroll
        for (int r = 0; r < 2; ++r) {
            int flat = r * 256 + tid;
            int row = flat >> 2, ch = flat & 3;
            const short* ga = A + (long)(m0 + row) * K + k0 + ch * 8;
            const short* gw = W + (long)(n0 + row) * K + k0 + ch * 8;
            int base = (r * 256 + wv * 64) * 8;
            glds16(ga, As[buf] + base);
            glds16(gw, Ws[buf] + base);
        }
    };

    stage(0, 0);   // prologue

    f32x4 acc[4][4] = {};

    for (int k0 = 0; k0 < K; k0 += 32) {
        const int buf = (k0 >> 5) & 1;
        __syncthreads();   // vmcnt(0): glds(k0) landed (issued 1 iter ago)

        bf16x8 af[4], wf[4];
#pragma unroll
        for (int i = 0; i < 4; ++i) {
            af[i] = *(const bf16x8*)(As[buf] + (wm * 64 + i * 16 + l16) * 32 + qd * 8);
            wf[i] = *(const bf16x8*)(Ws[buf] + (wn * 64 + i * 16 + l16) * 32 + qd * 8);
        }
        if (k0 + 32 < K) stage(k0 + 32, buf ^ 1);   // in flight through MFMAs

#pragma unroll
        for (int i = 0; i < 4; ++i)
#pragma unroll
            for (int j = 0; j < 4; ++j)
                acc[i][j] = __builtin_amdgcn_mfma_f32_16x16x32_bf16(
                    af[i], wf[j], acc[i][j], 0, 0, 0);
    }

    if (OUT == 2) {
        float* C = (float*)Cv;
#pragma unroll
        for (int i = 0; i < 4; ++i) {
            int row0 = m0 + wm * 64 + i * 16 + qd * 4;
#pragma unroll
            for (int j = 0; j < 4; ++j) {
                int col = n0 + wn * 64 + j * 16 + l16;
#pragma unroll
                for (int r = 0; r < 4; ++r)
                    C[(long)(row0 + r) * N + col] = acc[i][j][r];
            }
        }
    } else {  // OUT == 3
        if (n0 < NQK_) {
            short* C = (short*)Cv;
#pragma unroll
            for (int i = 0; i < 4; ++i) {
                int row0 = m0 + wm * 64 + i * 16 + qd * 4;
#pragma unroll
                for (int j = 0; j < 4; ++j) {
                    int col = n0 + wn * 64 + j * 16 + l16;
#pragma unroll
                    for (int r = 0; r < 4; ++r)
                        C[(long)(row0 + r) * NQK_ + col] = f2bf(acc[i][j][r]);
                }
            }
        } else {
            short* C = (short*)Cv2;
#pragma unroll
            for (int i = 0; i < 4; ++i) {
                int row0 = m0 + wm * 64 + i * 16 + qd * 4;
#pragma unroll
                for (int j = 0; j < 4; ++j) {
                    int vcol = n0 - NQK_ + wn * 64 + j * 16 + l16;
                    bf16x4 pk;
                    pk.x = f2bf(acc[i][j][0]); pk.y = f2bf(acc[i][j][1]);
                    pk.z = f2bf(acc[i][j][2]); pk.w = f2bf(acc[i][j][3]);
                    *(bf16x4*)(C + (long)vcol * M_ + row0) = pk;  // V^T
                }
            }
        }
    }
}

// ---------------------------------------------------------------------------
// RMSNorm + RoPE, in place on fused qk buffer (row stride NQK_).
// Q additionally pre-scaled by (1/sqrt(96))*log2(e) -> exp2-domain scores.
// ---------------------------------------------------------------------------
__global__ __launch_bounds__(256) void rms_rope(
    short* __restrict__ qk, const float* __restrict__ qw,
    const float* __restrict__ kw, const int* __restrict__ pos_ids)
{
    int wid  = (int)((blockIdx.x * 256 + threadIdx.x) >> 6);
    int lane = threadIdx.x & 63;

    short* v; const float* w; int row; float qs;
    if (wid < 65536) {                       // q: 4096 rows x 16 heads
        row = wid >> 4;
        v = qk + (long)row * NQK_ + (wid & 15) * 96;
        w = qw;
        qs = 0.14724444f;                    // (1/sqrt(96)) * log2(e)
    } else {                                 // k: 4096 rows x 4 heads
        int t = wid - 65536;
        row = t >> 2;
        v = qk + (long)row * NQK_ + 1536 + (t & 3) * 96;
        w = kw;
        qs = 1.0f;
    }

    float x0 = 0.f, x1 = 0.f;
    if (lane < 48) { x0 = bf2f(v[lane]); x1 = bf2f(v[lane + 48]); }
    float ss = x0 * x0 + x1 * x1;
#pragma unroll
    for (int off = 1; off < 64; off <<= 1) ss += __shfl_xor(ss, off, 64);
    float rr = rsqrtf(ss * (1.0f / 96.0f) + 1e-6f);

    if (lane < 48) {
        int pos = pos_ids[row];
        float y0 = (x0 * rr) * w[lane] * qs;
        float y1 = (x1 * rr) * w[lane + 48] * qs;
        float inv = exp2f(-(float)lane * (13.287712379549449f / 48.0f));
        float fr  = (float)pos * inv;
        float c, s;
        sincosf(fr, &s, &c);
        v[lane]      = f2bf(y0 * c - y1 * s);
        v[lane + 48] = f2bf(y1 * c + y0 * s);
    }
}

// ---------------------------------------------------------------------------
// Flash attention (causal, GQA 4:1). Triangle-paired q-tiles (33 units/block),
// double-buffered K/V LDS, DPP reductions, exp2-domain softmax, truncating
// P-pack with numerator/denominator-consistent l, conditional o-rescale.
// qk: fused (M x NQK_)  vt: (KV*VD x M)  out: (B,S,H*128) bf16
// ---------------------------------------------------------------------------
__global__ __launch_bounds__(256) void attn(
    const short* __restrict__ qk, const short* __restrict__ vt,
    short* __restrict__ out)
{
    __shared__ short Ks[2][64 * 104];    // 26.0 KB
    __shared__ short Vs[2][128 * 72];    // 36.0 KB
    __shared__ short Ps[4][16 * 72];     //  9.0 KB   (71 KB -> 2 blocks/CU)

    const int tid  = threadIdx.x;
    const int lane = tid & 63;
    const int wv   = tid >> 6;
    const int pair = blockIdx.x;          // 0..15
    const int bh   = blockIdx.y;          // 0..31
    const int b    = bh >> 4, h = bh & 15;
    const int kvh  = h >> 2;
    const int l16  = lane & 15;
    const int qd   = lane >> 4;
    const long bS  = (long)b * S_;

    const short* kbase = qk + bS * NQK_ + 1536 + kvh * 96;
    const short* vbase = vt + (long)kvh * 128 * (B_ * S_) + bS;

    auto loadK = [&](int k0, bf16x8* kr) {
#pragma unroll
        for (int r = 0; r < 3; ++r) {
            int flat = r * 256 + tid;
            int row = flat / 12, ch = flat % 12;
            kr[r] = *(const bf16x8*)(kbase + (long)(k0 + row) * NQK_ + ch * 8);
        }
    };
    auto loadV = [&](int k0, bf16x8* vr) {
#pragma unroll
        for (int r = 0; r < 4; ++r) {
            int flat = r * 256 + tid;
            int row = flat >> 3, ch = flat & 7;
            vr[r] = *(const bf16x8*)(vbase + (long)row * (B_ * S_) + k0 + ch * 8);
        }
    };
    auto storeKV = [&](int buf, bf16x8* kr, bf16x8* vr) {
#pragma unroll
        for (int r = 0; r < 3; ++r) {
            int flat = r * 256 + tid;
            int row = flat / 12, ch = flat % 12;
            *(bf16x8*)(Ks[buf] + row * 104 + ch * 8) = kr[r];
        }
#pragma unroll
        for (int r = 0; r < 4; ++r) {
            int flat = r * 256 + tid;
            int row = flat >> 3, ch = flat & 7;
            *(bf16x8*)(Vs[buf] + row * 72 + ch * 8) = vr[r];
        }
    };

#pragma unroll 1
    for (int pass = 0; pass < 2; ++pass) {
        const int qt = pass == 0 ? (31 - pair) : pair;
        const int q0 = qt * 64;

        bf16x8 qf[3];
        {
            int s = q0 + wv * 16 + l16;
            const short* qp = qk + (bS + s) * NQK_ + h * 96 + qd * 8;
            qf[0] = *(const bf16x8*)(qp);
            qf[1] = *(const bf16x8*)(qp + 32);
            qf[2] = *(const bf16x8*)(qp + 64);
        }

        float m_i[4], l_i[4];
        f32x4 o[8] = {};
#pragma unroll
        for (int r = 0; r < 4; ++r) { m_i[r] = -1e30f; l_i[r] = 0.f; }

        {
            bf16x8 kr[3], vr[4];
            loadK(0, kr); loadV(0, vr);
            __syncthreads();          // prior pass's LDS reads complete
            storeKV(0, kr, vr);
            __syncthreads();
        }

        for (int kt = 0; kt <= qt; ++kt) {
            const int buf = kt & 1;
            const bool more = (kt < qt);
            bf16x8 kn[3], vn[4];
            if (more) { loadK((kt + 1) * 64, kn); loadV((kt + 1) * 64, vn); }

            // S (exp2 domain): Q K^T
            f32x4 sa[4];
#pragma unroll
            for (int j = 0; j < 4; ++j) {
                f32x4 a = {};
#pragma unroll
                for (int f = 0; f < 3; ++f) {
                    bf16x8 kf = *(const bf16x8*)(Ks[buf] + (j * 16 + l16) * 104 + f * 32 + qd * 8);
                    a = __builtin_amdgcn_mfma_f32_16x16x32_bf16(qf[f], kf, a, 0, 0, 0);
                }
                sa[j] = a;
            }
            if (kt == qt) {   // causal mask, diagonal tile only
                int qi = wv * 16 + qd * 4;
#pragma unroll
                for (int j = 0; j < 4; ++j) {
                    int kj = j * 16 + l16;
#pragma unroll
                    for (int r = 0; r < 4; ++r)
                        if (kj > qi + r) sa[j][r] = -30000.0f;
                }
            }

            // online softmax
            float al[4], rs[4];
            bool need = false;
#pragma unroll
            for (int r = 0; r < 4; ++r) {
                float mx = rmax16(fmaxf(fmaxf(sa[0][r], sa[1][r]),
                                        fmaxf(sa[2][r], sa[3][r])));
                float mn = fmaxf(m_i[r], mx);
                al[r] = exp2f(m_i[r] - mn);
                m_i[r] = mn;
                need |= (al[r] < 1.0f);
            }
#pragma unroll
            for (int r = 0; r < 4; ++r) rs[r] = 0.f;
#pragma unroll
            for (int j = 0; j < 4; ++j)
#pragma unroll
                for (int r = 0; r < 4; ++r) {
                    float p = exp2f(sa[j][r] - m_i[r]);
                    unsigned pu = __float_as_uint(p);
                    Ps[wv][(qd * 4 + r) * 72 + j * 16 + l16] = (short)(pu >> 16);
                    rs[r] += __uint_as_float(pu & 0xffff0000u);  // consistent with P
                }
            if (__any(need)) {   // wave-uniform; skip when max unchanged
#pragma unroll
                for (int r = 0; r < 4; ++r) l_i[r] *= al[r];
#pragma unroll
                for (int t = 0; t < 8; ++t)
#pragma unroll
                    for (int r = 0; r < 4; ++r) o[t][r] *= al[r];
            }
#pragma unroll
            for (int r = 0; r < 4; ++r) l_i[r] += rsum16(rs[r]);

            // PV
            bf16x8 pf[2];
#pragma unroll
            for (int c = 0; c < 2; ++c)
                pf[c] = *(const bf16x8*)(&Ps[wv][l16 * 72 + c * 32 + qd * 8]);
#pragma unroll
            for (int t = 0; t < 8; ++t)
#pragma unroll
                for (int c = 0; c < 2; ++c) {
                    bf16x8 vf = *(const bf16x8*)(Vs[buf] + (t * 16 + l16) * 72 + c * 32 + qd * 8);
                    o[t] = __builtin_amdgcn_mfma_f32_16x16x32_bf16(pf[c], vf, o[t], 0, 0, 0);
                }

            if (more) {
                storeKV(buf ^ 1, kn, vn);
                __syncthreads();
            }
        }

        // epilogue: O / l
        float inv[4];
#pragma unroll
        for (int r = 0; r < 4; ++r) inv[r] = 1.0f / l_i[r];
#pragma unroll
        for (int t = 0; t < 8; ++t)
#pragma unroll
            for (int r = 0; r < 4; ++r) {
                int s = q0 + wv * 16 + qd * 4 + r;
                out[((bS + s) * H_ + h) * 128 + t * 16 + l16] =
                    f2bf(o[t][r] * inv[r]);
            }
    }
}

// ---------------------------------------------------------------------------
extern "C" void kernel_launch(void* const* d_in, const int* in_sizes, int n_in,
                              void* d_out, int out_size, void* d_ws, size_t ws_size,
                              hipStream_t stream)
{
    const float* hs  = (const float*)d_in[0];
    const int*   pos = (const int*)d_in[1];
    const float* Wq  = (const float*)d_in[2];
    const float* Wk  = (const float*)d_in[3];
    const float* Wv  = (const float*)d_in[4];
    const float* Wo  = (const float*)d_in[5];
    const float* qnw = (const float*)d_in[6];
    const float* knw = (const float*)d_in[7];
    float* out = (float*)d_out;
    short* ws  = (short*)d_ws;

    short* hsb   = ws;                         // 4096 x 2048
    short* Wqkvb = hsb + (long)M_ * D_;        // 2432 x 2048 (Wq|Wk|Wv rows)
    short* Wob   = Wqkvb + (long)2432 * D_;    // 2048 x 2048
    short* qk_ws = Wob + (long)D_ * 2048;      // 4096 x 1920 (q | k fused)
    short* vt_ws = qk_ws + (long)M_ * NQK_;    // 512 x 4096  (V^T)
    short* ao_ws = vt_ws + (long)512 * M_;     // 4096 x 2048

    cvt_all<<<17152, 256, 0, stream>>>(hs, Wq, Wk, Wv, Wo, ws);

    gemm_bt<3><<<dim3(M_ / 128, 2432 / 128), 256, 0, stream>>>(
        hsb, Wqkvb, qk_ws, vt_ws, M_, 2432, D_);

    rms_rope<<<(65536 + 16384) / 4, 256, 0, stream>>>(qk_ws, qnw, knw, pos);

    attn<<<dim3(16, 32), 256, 0, stream>>>(qk_ws, vt_ws, ao_ws);

    gemm_bt<2><<<dim3(M_ / 128, D_ / 128), 256, 0, stream>>>(
        ao_ws, Wob, (void*)out, nullptr, M_, D_, H_ * VD_);
}

// Round 6
// 316.942 us; speedup vs baseline: 1.1793x; 1.1793x over previous
//
#include <hip/hip_runtime.h>
#include <hip/hip_bf16.h>

#define B_   2
#define S_   2048
#define D_   2048
#define H_   16
#define KV_  4
#define KQD_ 96
#define VD_  128
#define NQK_ 1920            // H*KQD + KV*KQD = 1536 + 384
#define M_   4096            // B*S

typedef __attribute__((ext_vector_type(8))) short bf16x8;
typedef __attribute__((ext_vector_type(4))) short bf16x4;
typedef __attribute__((ext_vector_type(4))) float f32x4;

__device__ __forceinline__ short f2bf(float f) {
    union { float f; unsigned u; } v; v.f = f;
    unsigned r = (v.u + 0x7fffu + ((v.u >> 16) & 1u)) >> 16;
    return (short)r;
}
__device__ __forceinline__ float bf2f(short s) {
    union { unsigned u; float f; } v; v.u = ((unsigned)(unsigned short)s) << 16;
    return v.f;
}

__device__ __forceinline__ void glds16(const void* g, void* l) {
    __builtin_amdgcn_global_load_lds(
        (__attribute__((address_space(1))) void*)(g),
        (__attribute__((address_space(3))) void*)(l), 16, 0, 0);
}

// DPP-based 16-lane sum (epilogue only now)
template <int CTRL>
__device__ __forceinline__ float dppf(float x) {
    return __int_as_float(__builtin_amdgcn_update_dpp(
        0, __float_as_int(x), CTRL, 0xF, 0xF, true));
}
__device__ __forceinline__ float rsum16(float x) {
    x += dppf<0xB1>(x);     // quad_perm xor1
    x += dppf<0x4E>(x);     // quad_perm xor2
    x += dppf<0x124>(x);    // row_ror:4
    x += dppf<0x128>(x);    // row_ror:8
    return x;
}

// ---------------------------------------------------------------------------
// fp32 -> bf16 for all five inputs in one launch; dests contiguous in ws.
// ---------------------------------------------------------------------------
__global__ __launch_bounds__(256) void cvt_all(
    const float* __restrict__ hs, const float* __restrict__ wq,
    const float* __restrict__ wk, const float* __restrict__ wv,
    const float* __restrict__ wo, short* __restrict__ dst)
{
    int i = blockIdx.x * 256 + threadIdx.x;
    if (i >= 4390912) return;
    const float* s; int off;
    if      (i < 2097152) { s = hs; off = i; }
    else if (i < 2883584) { s = wq; off = i - 2097152; }
    else if (i < 3080192) { s = wk; off = i - 2883584; }
    else if (i < 3342336) { s = wv; off = i - 3080192; }
    else                  { s = wo; off = i - 3342336; }
    float4 v = ((const float4*)s)[off];
    bf16x4 o;
    o.x = f2bf(v.x); o.y = f2bf(v.y); o.z = f2bf(v.z); o.w = f2bf(v.w);
    ((bf16x4*)dst)[i] = o;
}

// ---------------------------------------------------------------------------
// GEMM: C[M x N] = A[M x K] * W[N x K]^T   (bf16 in, fp32 acc)
// Double-buffered LDS K-loop, ONE barrier per iter (proven win R5):
// glds(k+1) issued after frag reads of tile k, in flight through the MFMAs.
// OUT==2: fp32 row-major.  OUT==3: fused QKV (cols<NQK_ row-major into Cv,
// cols>=NQK_ transposed V^T into Cv2).
// ---------------------------------------------------------------------------
template <int OUT>
__global__ __launch_bounds__(256) void gemm_bt(
    const short* __restrict__ A, const short* __restrict__ W,
    void* __restrict__ Cv, void* __restrict__ Cv2, int M, int N, int K)
{
    __shared__ short As[2][128 * 32];   // 16 KB
    __shared__ short Ws[2][128 * 32];   // 16 KB

    const int tid  = threadIdx.x;
    const int wv   = tid >> 6;
    const int lane = tid & 63;
    const int wm   = wv >> 1, wn = wv & 1;
    const int m0   = blockIdx.x * 128;
    const int n0   = blockIdx.y * 128;
    const int l16  = lane & 15;
    const int qd   = lane >> 4;

    auto stage = [&](int k0, int buf) {
#pragma unroll
        for (int r = 0; r < 2; ++r) {
            int flat = r * 256 + tid;
            int row = flat >> 2, ch = flat & 3;
            const short* ga = A + (long)(m0 + row) * K + k0 + ch * 8;
            const short* gw = W + (long)(n0 + row) * K + k0 + ch * 8;
            int base = (r * 256 + wv * 64) * 8;
            glds16(ga, As[buf] + base);
            glds16(gw, Ws[buf] + base);
        }
    };

    stage(0, 0);   // prologue

    f32x4 acc[4][4] = {};

    for (int k0 = 0; k0 < K; k0 += 32) {
        const int buf = (k0 >> 5) & 1;
        __syncthreads();   // vmcnt(0): glds(k0) landed (issued 1 iter ago)

        bf16x8 af[4], wf[4];
#pragma unroll
        for (int i = 0; i < 4; ++i) {
            af[i] = *(const bf16x8*)(As[buf] + (wm * 64 + i * 16 + l16) * 32 + qd * 8);
            wf[i] = *(const bf16x8*)(Ws[buf] + (wn * 64 + i * 16 + l16) * 32 + qd * 8);
        }
        if (k0 + 32 < K) stage(k0 + 32, buf ^ 1);   // in flight through MFMAs

#pragma unroll
        for (int i = 0; i < 4; ++i)
#pragma unroll
            for (int j = 0; j < 4; ++j)
                acc[i][j] = __builtin_amdgcn_mfma_f32_16x16x32_bf16(
                    af[i], wf[j], acc[i][j], 0, 0, 0);
    }

    if (OUT == 2) {
        float* C = (float*)Cv;
#pragma unroll
        for (int i = 0; i < 4; ++i) {
            int row0 = m0 + wm * 64 + i * 16 + qd * 4;
#pragma unroll
            for (int j = 0; j < 4; ++j) {
                int col = n0 + wn * 64 + j * 16 + l16;
#pragma unroll
                for (int r = 0; r < 4; ++r)
                    C[(long)(row0 + r) * N + col] = acc[i][j][r];
            }
        }
    } else {  // OUT == 3
        if (n0 < NQK_) {
            short* C = (short*)Cv;
#pragma unroll
            for (int i = 0; i < 4; ++i) {
                int row0 = m0 + wm * 64 + i * 16 + qd * 4;
#pragma unroll
                for (int j = 0; j < 4; ++j) {
                    int col = n0 + wn * 64 + j * 16 + l16;
#pragma unroll
                    for (int r = 0; r < 4; ++r)
                        C[(long)(row0 + r) * NQK_ + col] = f2bf(acc[i][j][r]);
                }
            }
        } else {
            short* C = (short*)Cv2;
#pragma unroll
            for (int i = 0; i < 4; ++i) {
                int row0 = m0 + wm * 64 + i * 16 + qd * 4;
#pragma unroll
                for (int j = 0; j < 4; ++j) {
                    int vcol = n0 - NQK_ + wn * 64 + j * 16 + l16;
                    bf16x4 pk;
                    pk.x = f2bf(acc[i][j][0]); pk.y = f2bf(acc[i][j][1]);
                    pk.z = f2bf(acc[i][j][2]); pk.w = f2bf(acc[i][j][3]);
                    *(bf16x4*)(C + (long)vcol * M_ + row0) = pk;  // V^T
                }
            }
        }
    }
}

// ---------------------------------------------------------------------------
// RMSNorm + RoPE, in place on fused qk buffer (row stride NQK_).
// Q additionally pre-scaled by (1/sqrt(96))*log2(e) -> exp2-domain scores.
// ---------------------------------------------------------------------------
__global__ __launch_bounds__(256) void rms_rope(
    short* __restrict__ qk, const float* __restrict__ qw,
    const float* __restrict__ kw, const int* __restrict__ pos_ids)
{
    int wid  = (int)((blockIdx.x * 256 + threadIdx.x) >> 6);
    int lane = threadIdx.x & 63;

    short* v; const float* w; int row; float qs;
    if (wid < 65536) {                       // q: 4096 rows x 16 heads
        row = wid >> 4;
        v = qk + (long)row * NQK_ + (wid & 15) * 96;
        w = qw;
        qs = 0.14724444f;                    // (1/sqrt(96)) * log2(e)
    } else {                                 // k: 4096 rows x 4 heads
        int t = wid - 65536;
        row = t >> 2;
        v = qk + (long)row * NQK_ + 1536 + (t & 3) * 96;
        w = kw;
        qs = 1.0f;
    }

    float x0 = 0.f, x1 = 0.f;
    if (lane < 48) { x0 = bf2f(v[lane]); x1 = bf2f(v[lane + 48]); }
    float ss = x0 * x0 + x1 * x1;
#pragma unroll
    for (int off = 1; off < 64; off <<= 1) ss += __shfl_xor(ss, off, 64);
    float rr = rsqrtf(ss * (1.0f / 96.0f) + 1e-6f);

    if (lane < 48) {
        int pos = pos_ids[row];
        float y0 = (x0 * rr) * w[lane] * qs;
        float y1 = (x1 * rr) * w[lane + 48] * qs;
        float inv = exp2f(-(float)lane * (13.287712379549449f / 48.0f));
        float fr  = (float)pos * inv;
        float c, s;
        sincosf(fr, &s, &c);
        v[lane]      = f2bf(y0 * c - y1 * s);
        v[lane + 48] = f2bf(y1 * c + y0 * s);
    }
}

// ---------------------------------------------------------------------------
// Flash attention (causal, GQA 4:1). Triangle-paired q-tiles (33 units/block),
// double-buffered K/V LDS, exp2-domain STATIC-MAX softmax:
//   q,k are RMS-normalized (|q|=|k|=sqrt(96), RoPE is norm-preserving), so
//   score*log2e <= 96/sqrt(96)*log2e = 14.14 < M=14.5. p = exp2(s - M) needs
//   no running max, no o-rescale, and l reduces once in the epilogue.
// qk: fused (M x NQK_)  vt: (KV*VD x M)  out: (B,S,H*128) bf16
// ---------------------------------------------------------------------------
__global__ __launch_bounds__(256) void attn(
    const short* __restrict__ qk, const short* __restrict__ vt,
    short* __restrict__ out)
{
    __shared__ short Ks[2][64 * 104];    // 26.0 KB
    __shared__ short Vs[2][128 * 72];    // 36.0 KB
    __shared__ short Ps[4][16 * 72];     //  9.0 KB   (71 KB -> 2 blocks/CU)

    const int tid  = threadIdx.x;
    const int lane = tid & 63;
    const int wv   = tid >> 6;
    const int pair = blockIdx.x;          // 0..15
    const int bh   = blockIdx.y;          // 0..31
    const int b    = bh >> 4, h = bh & 15;
    const int kvh  = h >> 2;
    const int l16  = lane & 15;
    const int qd   = lane >> 4;
    const long bS  = (long)b * S_;

    const short* kbase = qk + bS * NQK_ + 1536 + kvh * 96;
    const short* vbase = vt + (long)kvh * 128 * (B_ * S_) + bS;

    auto loadK = [&](int k0, bf16x8* kr) {
#pragma unroll
        for (int r = 0; r < 3; ++r) {
            int flat = r * 256 + tid;
            int row = flat / 12, ch = flat % 12;
            kr[r] = *(const bf16x8*)(kbase + (long)(k0 + row) * NQK_ + ch * 8);
        }
    };
    auto loadV = [&](int k0, bf16x8* vr) {
#pragma unroll
        for (int r = 0; r < 4; ++r) {
            int flat = r * 256 + tid;
            int row = flat >> 3, ch = flat & 7;
            vr[r] = *(const bf16x8*)(vbase + (long)row * (B_ * S_) + k0 + ch * 8);
        }
    };
    auto storeKV = [&](int buf, bf16x8* kr, bf16x8* vr) {
#pragma unroll
        for (int r = 0; r < 3; ++r) {
            int flat = r * 256 + tid;
            int row = flat / 12, ch = flat % 12;
            *(bf16x8*)(Ks[buf] + row * 104 + ch * 8) = kr[r];
        }
#pragma unroll
        for (int r = 0; r < 4; ++r) {
            int flat = r * 256 + tid;
            int row = flat >> 3, ch = flat & 7;
            *(bf16x8*)(Vs[buf] + row * 72 + ch * 8) = vr[r];
        }
    };

#pragma unroll 1
    for (int pass = 0; pass < 2; ++pass) {
        const int qt = pass == 0 ? (31 - pair) : pair;
        const int q0 = qt * 64;

        bf16x8 qf[3];
        {
            int s = q0 + wv * 16 + l16;
            const short* qp = qk + (bS + s) * NQK_ + h * 96 + qd * 8;
            qf[0] = *(const bf16x8*)(qp);
            qf[1] = *(const bf16x8*)(qp + 32);
            qf[2] = *(const bf16x8*)(qp + 64);
        }

        float rs[4] = {0.f, 0.f, 0.f, 0.f};   // un-reduced l accumulators
        f32x4 o[8] = {};

        {
            bf16x8 kr[3], vr[4];
            loadK(0, kr); loadV(0, vr);
            __syncthreads();          // prior pass's LDS reads complete
            storeKV(0, kr, vr);
            __syncthreads();
        }

        for (int kt = 0; kt <= qt; ++kt) {
            const int buf = kt & 1;
            const bool more = (kt < qt);
            bf16x8 kn[3], vn[4];
            if (more) { loadK((kt + 1) * 64, kn); loadV((kt + 1) * 64, vn); }

            // S (exp2 domain, statically bounded by 14.14): Q K^T
            f32x4 sa[4];
#pragma unroll
            for (int j = 0; j < 4; ++j) {
                f32x4 a = {};
#pragma unroll
                for (int f = 0; f < 3; ++f) {
                    bf16x8 kf = *(const bf16x8*)(Ks[buf] + (j * 16 + l16) * 104 + f * 32 + qd * 8);
                    a = __builtin_amdgcn_mfma_f32_16x16x32_bf16(qf[f], kf, a, 0, 0, 0);
                }
                sa[j] = a;
            }
            if (kt == qt) {   // causal mask, diagonal tile only
                int qi = wv * 16 + qd * 4;
#pragma unroll
                for (int j = 0; j < 4; ++j) {
                    int kj = j * 16 + l16;
#pragma unroll
                    for (int r = 0; r < 4; ++r)
                        if (kj > qi + r) sa[j][r] = -30000.0f;
                }
            }

            // static-max softmax: p = exp2(s - M); no max tracking, no rescale
#pragma unroll
            for (int j = 0; j < 4; ++j)
#pragma unroll
                for (int r = 0; r < 4; ++r) {
                    float p = exp2f(sa[j][r] - 14.5f);
                    rs[r] += p;
                    Ps[wv][(qd * 4 + r) * 72 + j * 16 + l16] = f2bf(p);
                }

            // PV
            bf16x8 pf[2];
#pragma unroll
            for (int c = 0; c < 2; ++c)
                pf[c] = *(const bf16x8*)(&Ps[wv][l16 * 72 + c * 32 + qd * 8]);
#pragma unroll
            for (int t = 0; t < 8; ++t)
#pragma unroll
                for (int c = 0; c < 2; ++c) {
                    bf16x8 vf = *(const bf16x8*)(Vs[buf] + (t * 16 + l16) * 72 + c * 32 + qd * 8);
                    o[t] = __builtin_amdgcn_mfma_f32_16x16x32_bf16(pf[c], vf, o[t], 0, 0, 0);
                }

            if (more) {
                storeKV(buf ^ 1, kn, vn);
                __syncthreads();
            }
        }

        // epilogue: reduce l once, O / l
        float inv[4];
#pragma unroll
        for (int r = 0; r < 4; ++r) inv[r] = 1.0f / rsum16(rs[r]);
#pragma unroll
        for (int t = 0; t < 8; ++t)
#pragma unroll
            for (int r = 0; r < 4; ++r) {
                int s = q0 + wv * 16 + qd * 4 + r;
                out[((bS + s) * H_ + h) * 128 + t * 16 + l16] =
                    f2bf(o[t][r] * inv[r]);
            }
    }
}

// ---------------------------------------------------------------------------
extern "C" void kernel_launch(void* const* d_in, const int* in_sizes, int n_in,
                              void* d_out, int out_size, void* d_ws, size_t ws_size,
                              hipStream_t stream)
{
    const float* hs  = (const float*)d_in[0];
    const int*   pos = (const int*)d_in[1];
    const float* Wq  = (const float*)d_in[2];
    const float* Wk  = (const float*)d_in[3];
    const float* Wv  = (const float*)d_in[4];
    const float* Wo  = (const float*)d_in[5];
    const float* qnw = (const float*)d_in[6];
    const float* knw = (const float*)d_in[7];
    float* out = (float*)d_out;
    short* ws  = (short*)d_ws;

    short* hsb   = ws;                         // 4096 x 2048
    short* Wqkvb = hsb + (long)M_ * D_;        // 2432 x 2048 (Wq|Wk|Wv rows)
    short* Wob   = Wqkvb + (long)2432 * D_;    // 2048 x 2048
    short* qk_ws = Wob + (long)D_ * 2048;      // 4096 x 1920 (q | k fused)
    short* vt_ws = qk_ws + (long)M_ * NQK_;    // 512 x 4096  (V^T)
    short* ao_ws = vt_ws + (long)512 * M_;     // 4096 x 2048

    cvt_all<<<17152, 256, 0, stream>>>(hs, Wq, Wk, Wv, Wo, ws);

    gemm_bt<3><<<dim3(M_ / 128, 2432 / 128), 256, 0, stream>>>(
        hsb, Wqkvb, qk_ws, vt_ws, M_, 2432, D_);

    rms_rope<<<(65536 + 16384) / 4, 256, 0, stream>>>(qk_ws, qnw, knw, pos);

    attn<<<dim3(16, 32), 256, 0, stream>>>(qk_ws, vt_ws, ao_ws);

    gemm_bt<2><<<dim3(M_ / 128, D_ / 128), 256, 0, stream>>>(
        ao_ws, Wob, (void*)out, nullptr, M_, D_, H_ * VD_);
}